// Round 16
// baseline (246.808 us; speedup 1.0000x reference)
//
#include <hip/hip_runtime.h>
#include <hip/hip_bf16.h>

// ---------------------------------------------------------------------------
// GQA attention block: y = Attn(RoPE(xWq^T), RoPE(xWk^T), xWv^T) Wo^T
// B=2, S=2048, D=2048, Hq=32, Hkv=8, hd=64, G=4, non-causal, scale=1/8.
// Pipeline (4 kernels): prep(cast+table) -> gemm_qkv(+fused rope/layout)
//                       -> attn (128-kv phase, 2-deep stagger) -> gemm_o.
// ---------------------------------------------------------------------------

typedef __attribute__((ext_vector_type(8))) short short8;
typedef __attribute__((ext_vector_type(4))) float f32x4;
typedef __attribute__((ext_vector_type(16))) float f32x16;

#define MFMA16(A, B, C) __builtin_amdgcn_mfma_f32_16x16x32_bf16((A), (B), (C), 0, 0, 0)
#define MFMA32(A, B, C) __builtin_amdgcn_mfma_f32_32x32x16_bf16((A), (B), (C), 0, 0, 0)

__device__ __forceinline__ ushort f2bf(float f) {
  __hip_bfloat16 h = __float2bfloat16(f);
  return __builtin_bit_cast(ushort, h);
}

// Raw v_exp_f32 (exp2). OCML's exp2f is a multi-instr sequence; this is 1.
__device__ __forceinline__ float fexp2(float x) {
#if __has_builtin(__builtin_amdgcn_exp2f)
  return __builtin_amdgcn_exp2f(x);
#else
  float r;
  asm("v_exp_f32 %0, %1" : "=v"(r) : "v"(x));
  return r;
#endif
}

__device__ __forceinline__ void gload_lds16(const void* g, void* l) {
  __builtin_amdgcn_global_load_lds(
      (const __attribute__((address_space(1))) unsigned int*)g,
      (__attribute__((address_space(3))) unsigned int*)l, 16, 0, 0);
}

// ---------------- fused prep: fp32->bf16 casts + RoPE table ----------------
__global__ __launch_bounds__(256) void prep_kernel(
    const float* __restrict__ x, const float* __restrict__ Wq,
    const float* __restrict__ Wk, const float* __restrict__ Wv,
    const float* __restrict__ Wo, ushort* __restrict__ xbf,
    ushort* __restrict__ wqbf, ushort* __restrict__ wkbf,
    ushort* __restrict__ wvbf, ushort* __restrict__ wobf,
    float* __restrict__ tc, float* __restrict__ ts) {
  const int blk = blockIdx.x;
  if (blk < 9216) {
    const float* src;
    ushort* dst;
    int t;
    if (blk < 4096) {
      src = x; dst = xbf; t = blk * 256 + threadIdx.x;
    } else if (blk < 6144) {
      src = Wq; dst = wqbf; t = (blk - 4096) * 256 + threadIdx.x;
    } else if (blk < 6656) {
      src = Wk; dst = wkbf; t = (blk - 6144) * 256 + threadIdx.x;
    } else if (blk < 7168) {
      src = Wv; dst = wvbf; t = (blk - 6656) * 256 + threadIdx.x;
    } else {
      src = Wo; dst = wobf; t = (blk - 7168) * 256 + threadIdx.x;
    }
    const float4* p = (const float4*)src;
    float4 a = p[t * 2], b = p[t * 2 + 1];
    int4 o;
    o.x = (int)f2bf(a.x) | ((int)f2bf(a.y) << 16);
    o.y = (int)f2bf(a.z) | ((int)f2bf(a.w) << 16);
    o.z = (int)f2bf(b.x) | ((int)f2bf(b.y) << 16);
    o.w = (int)f2bf(b.z) | ((int)f2bf(b.w) << 16);
    ((int4*)dst)[t] = o;
  } else {
    int t = (blk - 9216) * 256 + threadIdx.x;  // 2048*32
    int j = t & 31, s = t >> 5;
    float freq = powf(10000.0f, -(float)j * (1.0f / 32.0f));
    float ang = (float)s * freq;
    tc[t] = cosf(ang);
    ts[t] = sinf(ang);
  }
}

// ---------------- 128x128 bf16 GEMM core, BK=64, XOR-8 swizzled LDS --------
// Single-buffered variant (2 barriers/step) — used by gemm_qkv whose 768-tile
// grid fits exactly 3 blocks/CU at 32KB LDS.
__device__ __forceinline__ void gemm_core(const ushort* __restrict__ A,
                                          const ushort* __restrict__ Bt,
                                          int row0, int col0, int K,
                                          f32x4 (&acc)[4][4]) {
  __shared__ __align__(16) ushort As[8192];  // [128 rows][8 chunks of 16B]
  __shared__ __align__(16) ushort Bs[8192];
  const int t = threadIdx.x;
  const int lane = t & 63, wid = t >> 6;
  const int lr = lane & 15, lh = lane >> 4;
  const int wm = wid >> 1, wn = wid & 1;
#pragma unroll
  for (int i = 0; i < 4; ++i)
#pragma unroll
    for (int j = 0; j < 4; ++j) acc[i][j] = (f32x4){0.f, 0.f, 0.f, 0.f};

  const int srow = t >> 3, scg = (t & 7) ^ (srow & 7);
  const ushort* Asrc = A + (size_t)(row0 + srow) * K + scg * 8;
  const ushort* Bsrc = Bt + (size_t)(col0 + srow) * K + scg * 8;
  char* AsB = (char*)As + wid * 1024;
  char* BsB = (char*)Bs + wid * 1024;
  const int s7a = lr & 7;

  for (int k0 = 0; k0 < K; k0 += 64) {
    __syncthreads();  // previous iteration's reads done
#pragma unroll
    for (int i = 0; i < 4; ++i) {
      gload_lds16(Asrc + (size_t)(32 * i) * K + k0, AsB + i * 4096);
      gload_lds16(Bsrc + (size_t)(32 * i) * K + k0, BsB + i * 4096);
    }
    __syncthreads();  // staging visible

    short8 af[4][2];
#pragma unroll
    for (int fm = 0; fm < 4; ++fm)
#pragma unroll
      for (int kk = 0; kk < 2; ++kk)
        af[fm][kk] = *(const short8*)((const char*)As +
                                      ((wm * 64 + fm * 16 + lr) << 7) +
                                      (((kk * 4 + lh) ^ s7a) << 4));
#pragma unroll
    for (int kk = 0; kk < 2; ++kk)
#pragma unroll
      for (int fn = 0; fn < 4; ++fn) {
        short8 bf_ = *(const short8*)((const char*)Bs +
                                      ((wn * 64 + fn * 16 + lr) << 7) +
                                      (((kk * 4 + lh) ^ s7a) << 4));
#pragma unroll
        for (int fm = 0; fm < 4; ++fm)
          acc[fm][fn] = MFMA16(af[fm][kk], bf_, acc[fm][fn]);
      }
  }
}

// Double-buffered variant with COUNTED vmcnt (T3/T4): 16 loads in flight at
// steady state, vmcnt(8) per step (never 0 until the last tile). LDS 64KB ->
// 2 blocks/CU; used by gemm_o whose 512-block grid is exactly 2/CU.
__device__ __forceinline__ void gemm_core_db(const ushort* __restrict__ A,
                                             const ushort* __restrict__ Bt,
                                             int row0, int col0, int K,
                                             f32x4 (&acc)[4][4]) {
  __shared__ __align__(16) ushort As[16384];  // 2 x [128 rows][8 chunks]
  __shared__ __align__(16) ushort Bs[16384];
  const int t = threadIdx.x;
  const int lane = t & 63, wid = t >> 6;
  const int lr = lane & 15, lh = lane >> 4;
  const int wm = wid >> 1, wn = wid & 1;
#pragma unroll
  for (int i = 0; i < 4; ++i)
#pragma unroll
    for (int j = 0; j < 4; ++j) acc[i][j] = (f32x4){0.f, 0.f, 0.f, 0.f};

  const int srow = t >> 3, scg = (t & 7) ^ (srow & 7);
  const ushort* Asrc = A + (size_t)(row0 + srow) * K + scg * 8;
  const ushort* Bsrc = Bt + (size_t)(col0 + srow) * K + scg * 8;
  const int s7a = lr & 7;

#define GSTAGE(PAR, KOFF)                                                    \
  do {                                                                       \
    char* a_ = (char*)As + (PAR) * 16384 + wid * 1024;                       \
    char* b_ = (char*)Bs + (PAR) * 16384 + wid * 1024;                       \
    _Pragma("unroll") for (int i_ = 0; i_ < 4; ++i_) {                       \
      gload_lds16(Asrc + (size_t)(32 * i_) * K + (KOFF), a_ + i_ * 4096);    \
      gload_lds16(Bsrc + (size_t)(32 * i_) * K + (KOFF), b_ + i_ * 4096);    \
    }                                                                        \
  } while (0)

  GSTAGE(0, 0);
  GSTAGE(1, 64);
  const int nstep = K >> 6;
  for (int it = 0; it < nstep; ++it) {
    if (it + 1 < nstep)
      asm volatile("s_waitcnt vmcnt(8)" ::: "memory");
    else
      asm volatile("s_waitcnt vmcnt(0)" ::: "memory");
    __builtin_amdgcn_s_barrier();  // all waves staged tile 'it'
    {
      const char* ab_ = (const char*)As + (it & 1) * 16384;
      const char* bb_ = (const char*)Bs + (it & 1) * 16384;
      short8 af[4][2];
#pragma unroll
      for (int fm = 0; fm < 4; ++fm)
#pragma unroll
        for (int kk = 0; kk < 2; ++kk)
          af[fm][kk] = *(const short8*)(ab_ + ((wm * 64 + fm * 16 + lr) << 7) +
                                        (((kk * 4 + lh) ^ s7a) << 4));
#pragma unroll
      for (int kk = 0; kk < 2; ++kk)
#pragma unroll
        for (int fn = 0; fn < 4; ++fn) {
          short8 bf_ = *(const short8*)(bb_ + ((wn * 64 + fn * 16 + lr) << 7) +
                                        (((kk * 4 + lh) ^ s7a) << 4));
#pragma unroll
          for (int fm = 0; fm < 4; ++fm)
            acc[fm][fn] = MFMA16(af[fm][kk], bf_, acc[fm][fn]);
        }
    }
    __builtin_amdgcn_s_barrier();  // all waves done reading buf (it&1)
    if (it + 2 < nstep) GSTAGE(it & 1, (it + 2) * 64);
  }
#undef GSTAGE
}

// QKV projection with fused RoPE + head-split + V-transpose epilogue.
// Q out: [B][32][S][64] bf16 scaled by 1/(8*ln2); K out: [B][8][S][64];
// V out: [B][8][64][S] (transposed).
__global__ __launch_bounds__(256) void gemm_qkv_kernel(
    const ushort* __restrict__ xbf, const ushort* __restrict__ wq,
    const ushort* __restrict__ wk, const ushort* __restrict__ wv,
    ushort* __restrict__ Qo, ushort* __restrict__ Ko, ushort* __restrict__ Vo,
    const float* __restrict__ tabc, const float* __restrict__ tabs) {
  int bx = blockIdx.x % 24, by = blockIdx.x / 24;
  const ushort* Bt;
  int cb;
  if (bx < 16) {
    Bt = wq; cb = bx;
  } else if (bx < 20) {
    Bt = wk; cb = bx - 16;
  } else {
    Bt = wv; cb = bx - 20;
  }
  f32x4 acc[4][4];
  gemm_core(xbf, Bt, by * 128, cb * 128, 2048, acc);

  const int lane = threadIdx.x & 63, wid = threadIdx.x >> 6;
  const int lr = lane & 15, lh = lane >> 4;
  const int wm = wid >> 1, wn = wid & 1;
  const int srow0 = by * 128 + wm * 64 + lh * 4;

  if (bx >= 20) {
    const int kv = cb * 2 + wn;
#pragma unroll
    for (int fm = 0; fm < 4; ++fm) {
      int srow = srow0 + fm * 16;
      int bb = srow >> 11, s = srow & 2047;
#pragma unroll
      for (int fn = 0; fn < 4; ++fn) {
        int d = fn * 16 + lr;
        ushort4 o;
        o.x = f2bf(acc[fm][fn][0]);
        o.y = f2bf(acc[fm][fn][1]);
        o.z = f2bf(acc[fm][fn][2]);
        o.w = f2bf(acc[fm][fn][3]);
        *(ushort4*)&Vo[((size_t)((bb * 8 + kv) * 64 + d)) * 2048 + s] = o;
      }
    }
  } else {
    ushort* dst;
    int nh, h;
    float scale;
    if (bx < 16) {
      dst = Qo; nh = 32; h = bx * 2 + wn;
      scale = 0.125f * 1.44269504088896340736f;  // softmax scale * 1/ln2
    } else {
      dst = Ko; nh = 8; h = cb * 2 + wn; scale = 1.0f;
    }
#pragma unroll
    for (int fm = 0; fm < 4; ++fm) {
      int srow = srow0 + fm * 16;
      int bb = srow >> 11, sbase = srow & 2047;
      size_t obase = (size_t)(bb * nh + h) * 2048;
#pragma unroll
      for (int fn = 0; fn < 2; ++fn) {
        int j = fn * 16 + lr;
#pragma unroll
        for (int r = 0; r < 4; ++r) {
          int s = sbase + r;
          float c = tabc[s * 32 + j], sn = tabs[s * 32 + j];
          float x1 = acc[fm][fn][r], x2 = acc[fm][fn + 2][r];
          ushort* po = &dst[(obase + s) * 64 + j];
          po[0] = f2bf((x1 * c - x2 * sn) * scale);
          po[32] = f2bf((x2 * c + x1 * sn) * scale);
        }
      }
    }
  }
}

__global__ __launch_bounds__(256, 2) void gemm_o_kernel(const ushort* __restrict__ A,
                                                        const ushort* __restrict__ Wo,
                                                        float* __restrict__ C) {
  int bx = blockIdx.x & 15, by = blockIdx.x >> 4;
  int row0 = by * 128, col0 = bx * 128;
  f32x4 acc[4][4];
  gemm_core_db(A, Wo, row0, col0, 2048, acc);
  const int lane = threadIdx.x & 63, wid = threadIdx.x >> 6;
  const int lr = lane & 15, lh = lane >> 4;
  const int wm = wid >> 1, wn = wid & 1;
#pragma unroll
  for (int fm = 0; fm < 4; ++fm) {
    int r0 = row0 + wm * 64 + fm * 16 + lh * 4;
#pragma unroll
    for (int fn = 0; fn < 4; ++fn) {
      int cc = col0 + wn * 64 + fn * 16 + lr;
#pragma unroll
      for (int r = 0; r < 4; ++r) C[(size_t)(r0 + r) * 2048 + cc] = acc[fm][fn][r];
    }
  }
}

// ---------------- flash attention: 128-kv phases, 2-deep stagger -----------
// Q: [B][32][S][64] bf16 pre-scaled; K: [B][8][S][64]; Vt: [B][8][64][S];
// O: [B*S][2048] bf16. Block = 4 waves = 4 q-heads of one GQA group; each
// wave owns TWO 32-row q-tiles. PHASE = 128 kv rows (4 subtiles) per barrier
// iteration (16 barriers instead of 32). Subtile schedule is 2-deep: at most
// TWO score-pairs live (round-11 register profile — R12's 4-deep spilled),
// while each subtile's softmax still overlaps the next subtile's QK MFMAs.
// Softmax is UNNORMALIZED exp2 (scores bounded; sums cancel in /ls).
__global__ __launch_bounds__(256, 2) void attn_kernel(const ushort* __restrict__ Q,
                                                      const ushort* __restrict__ Kg,
                                                      const ushort* __restrict__ Vt,
                                                      ushort* __restrict__ O) {
  // K dbuf @ 0/16384 (16KB each), V dbuf @ 32768/49152 (16KB each) = 64KB.
  __shared__ __align__(16) char smem_c[65536];
  const int tid = threadIdx.x;
  const int lane = tid & 63;
  const int wid = tid >> 6;
  const int bid = ((blockIdx.x & 7) << 6) | (blockIdx.x >> 3);  // XCD swizzle
  const int qp = bid & 31;
  const int kvh = (bid >> 5) & 7;
  const int b = bid >> 8;
  const int h = kvh * 4 + wid;  // wave = one q-head of the group
  const int q0 = qp * 64;      // wave covers q0..q0+63 (two 32-row tiles)
  const int l31 = lane & 31;
  const int hi = lane >> 5;

  const ushort* Qp = Q + ((size_t)((b * 32 + h) * 2048 + q0)) * 64;
  const ushort* Kp = Kg + ((size_t)((b * 8 + kvh) * 2048)) * 64;
  const ushort* Vp = Vt + ((size_t)((b * 8 + kvh) * 64)) * 2048;

  // Staging (pre-swizzled global, linear LDS dest). K phase tile =
  // [128 kv][8 chunks16B] = 16KB; V phase tile = 2 x [64 d][64 kv] = 16KB.
  const int srow = tid >> 3, scg = (tid & 7) ^ (srow & 7);
  const ushort* Kst = Kp + (size_t)srow * 64 + scg * 8;
  const ushort* Vst = Vp + (size_t)srow * 2048 + scg * 8;

#define STAGE(PAR, KV0)                                                     \
  do {                                                                      \
    char* kd_ = smem_c + (PAR) * 16384 + wid * 1024;                        \
    char* vd_ = smem_c + 32768 + (PAR) * 16384 + wid * 1024;                \
    gload_lds16(Kst + (size_t)(KV0) * 64, kd_);                             \
    gload_lds16(Kst + (size_t)((KV0) + 32) * 64, kd_ + 4096);               \
    gload_lds16(Kst + (size_t)((KV0) + 64) * 64, kd_ + 8192);               \
    gload_lds16(Kst + (size_t)((KV0) + 96) * 64, kd_ + 12288);              \
    gload_lds16(Vst + (KV0), vd_);                                          \
    gload_lds16(Vst + 32 * 2048 + (KV0), vd_ + 4096);                       \
    gload_lds16(Vst + (KV0) + 64, vd_ + 8192);                              \
    gload_lds16(Vst + 32 * 2048 + (KV0) + 64, vd_ + 12288);                 \
  } while (0)

  STAGE(0, 0);  // phase 0 in flight immediately

  // Q B-frags for the two q-tiles.
  const short8 qfA0 = *(const short8*)(Qp + (size_t)l31 * 64 + 0 + hi * 8);
  const short8 qfA1 = *(const short8*)(Qp + (size_t)l31 * 64 + 16 + hi * 8);
  const short8 qfA2 = *(const short8*)(Qp + (size_t)l31 * 64 + 32 + hi * 8);
  const short8 qfA3 = *(const short8*)(Qp + (size_t)l31 * 64 + 48 + hi * 8);
  const short8 qfB0 = *(const short8*)(Qp + (size_t)(32 + l31) * 64 + 0 + hi * 8);
  const short8 qfB1 = *(const short8*)(Qp + (size_t)(32 + l31) * 64 + 16 + hi * 8);
  const short8 qfB2 = *(const short8*)(Qp + (size_t)(32 + l31) * 64 + 32 + hi * 8);
  const short8 qfB3 = *(const short8*)(Qp + (size_t)(32 + l31) * 64 + 48 + hi * 8);

  const int s7 = l31 & 7;
  const int ok0 = l31 * 128 + (((0 + hi) ^ s7) << 4);
  const int ok1 = l31 * 128 + (((2 + hi) ^ s7) << 4);
  const int ok2 = l31 * 128 + (((4 + hi) ^ s7) << 4);
  const int ok3 = l31 * 128 + (((6 + hi) ^ s7) << 4);

  f32x16 accA0, accA1, accB0, accB1, kz;
#pragma unroll
  for (int r = 0; r < 16; ++r) {
    accA0[r] = 0.f;
    accA1[r] = 0.f;
    accB0[r] = 0.f;
    accB1[r] = 0.f;
    kz[r] = 0.f;
  }
  float lshA = 0.f, lshB = 0.f;  // lane-half unnormalized sums

// QK^T for one 32-kv subtile, BOTH q-tiles; each K frag read feeds 2 MFMAs.
#define QK2(STA, STB, KOFF)                                  \
  do {                                                       \
    const char* kb_ = smem_c + (KOFF);                       \
    short8 kf_ = *(const short8*)(kb_ + ok0);                \
    __builtin_amdgcn_s_setprio(1);                           \
    STA = MFMA32(kf_, qfA0, kz);                             \
    STB = MFMA32(kf_, qfB0, kz);                             \
    kf_ = *(const short8*)(kb_ + ok1);                       \
    STA = MFMA32(kf_, qfA1, STA);                            \
    STB = MFMA32(kf_, qfB1, STB);                            \
    kf_ = *(const short8*)(kb_ + ok2);                       \
    STA = MFMA32(kf_, qfA2, STA);                            \
    STB = MFMA32(kf_, qfB2, STB);                            \
    kf_ = *(const short8*)(kb_ + ok3);                       \
    STA = MFMA32(kf_, qfA3, STA);                            \
    STB = MFMA32(kf_, qfB3, STB);                            \
    __builtin_amdgcn_s_setprio(0);                           \
  } while (0)

// Unnormalized softmax: ST -> P fragments (F0,F1) + half-sum LSH.
#define SMX(ST, F0, F1, LSH)                                                  \
  do {                                                                        \
    float ps_ = 0.f;                                                          \
    uint pk0_, pk1_, pk2_, pk3_, pk4_, pk5_, pk6_, pk7_;                      \
    _Pragma("unroll") for (int j = 0; j < 8; ++j) {                           \
      float pa_ = fexp2(ST[2 * j]);                                           \
      float pb_ = fexp2(ST[2 * j + 1]);                                       \
      ps_ += pa_ + pb_;                                                       \
      uint w_ = __builtin_amdgcn_perm(__builtin_bit_cast(uint, pb_),          \
                                      __builtin_bit_cast(uint, pa_),          \
                                      0x07060302u);                           \
      switch (j) {                                                            \
        case 0: pk0_ = w_; break;                                             \
        case 1: pk1_ = w_; break;                                             \
        case 2: pk2_ = w_; break;                                             \
        case 3: pk3_ = w_; break;                                             \
        case 4: pk4_ = w_; break;                                             \
        case 5: pk5_ = w_; break;                                             \
        case 6: pk6_ = w_; break;                                             \
        default: pk7_ = w_; break;                                            \
      }                                                                       \
    }                                                                         \
    LSH += ps_;                                                               \
    uint u0_ = hi ? pk0_ : pk2_; u0_ = __shfl_xor(u0_, 32);                   \
    uint u1_ = hi ? pk1_ : pk3_; u1_ = __shfl_xor(u1_, 32);                   \
    uint u2_ = hi ? pk4_ : pk6_; u2_ = __shfl_xor(u2_, 32);                   \
    uint u3_ = hi ? pk5_ : pk7_; u3_ = __shfl_xor(u3_, 32);                   \
    F0.u[0] = hi ? u0_ : pk0_;                                                \
    F0.u[1] = hi ? u1_ : pk1_;                                                \
    F0.u[2] = hi ? pk2_ : u0_;                                                \
    F0.u[3] = hi ? pk3_ : u1_;                                                \
    F1.u[0] = hi ? u2_ : pk4_;                                                \
    F1.u[1] = hi ? u3_ : pk5_;                                                \
    F1.u[2] = hi ? pk6_ : u2_;                                                \
    F1.u[3] = hi ? pk7_ : u3_;                                                \
  } while (0)

// Softmax + PV for one subtile, both q-tiles; V reads shared.
#define SMPV2(STA, STB, VOFF, VSX)                                           \
  do {                                                                       \
    union { uint u[4]; short8 s; } fA0_, fA1_, fB0_, fB1_;                   \
    SMX(STA, fA0_, fA1_, lshA);                                              \
    SMX(STB, fB0_, fB1_, lshB);                                              \
    const char* vb_ = smem_c + (VOFF);                                       \
    short8 v0_ = *(const short8*)(vb_ + (ok0 ^ (VSX)));                      \
    short8 v1_ = *(const short8*)(vb_ + (ok1 ^ (VSX)));                      \
    __builtin_amdgcn_s_setprio(1);                                           \
    accA0 = MFMA32(v0_, fA0_.s, accA0);                                      \
    accA0 = MFMA32(v1_, fA1_.s, accA0);                                      \
    accB0 = MFMA32(v0_, fB0_.s, accB0);                                      \
    accB0 = MFMA32(v1_, fB1_.s, accB0);                                      \
    __builtin_amdgcn_s_setprio(0);                                           \
    v0_ = *(const short8*)(vb_ + (ok0 ^ (VSX)) + 4096);                      \
    v1_ = *(const short8*)(vb_ + (ok1 ^ (VSX)) + 4096);                      \
    __builtin_amdgcn_s_setprio(1);                                           \
    accA1 = MFMA32(v0_, fA0_.s, accA1);                                      \
    accA1 = MFMA32(v1_, fA1_.s, accA1);                                      \
    accB1 = MFMA32(v0_, fB0_.s, accB1);                                      \
    accB1 = MFMA32(v1_, fB1_.s, accB1);                                      \
    __builtin_amdgcn_s_setprio(0);                                           \
  } while (0)

  for (int t = 0; t < 16; ++t) {
    asm volatile("s_waitcnt vmcnt(0)" ::: "memory");  // my phase-t loads landed
    __builtin_amdgcn_s_barrier();  // all waves: phase t staged, buf^1 readers done
    if (t < 15) STAGE((t + 1) & 1, (t + 1) * 128);  // prefetch under compute
    {
      const int kb = (t & 1) * 16384;
      const int vb = 32768 + (t & 1) * 16384;
      // 2-deep stagger: at most two score-pairs live (st0*, st1* reused for
      // subtiles 2,3). Each SMPV overlaps the following QK's MFMA stream.
      f32x16 st0A_, st0B_, st1A_, st1B_;
      QK2(st0A_, st0B_, kb);               // s0
      QK2(st1A_, st1B_, kb + 4096);        // s1
      SMPV2(st0A_, st0B_, vb, 0);          // s0  (st0 free)
      QK2(st0A_, st0B_, kb + 8192);        // s2 -> st0
      SMPV2(st1A_, st1B_, vb, 64);         // s1  (st1 free)
      QK2(st1A_, st1B_, kb + 12288);       // s3 -> st1
      SMPV2(st0A_, st0B_, vb + 8192, 0);   // s2
      SMPV2(st1A_, st1B_, vb + 8192, 64);  // s3
    }
  }
#undef STAGE
#undef QK2
#undef SMX
#undef SMPV2

  const float lsA = lshA + __shfl_xor(lshA, 32);
  const float lsB = lshB + __shfl_xor(lshB, 32);
  const float invA = 1.0f / lsA;
  const float invB = 1.0f / lsB;
  ushort* ObA = O + (size_t)(b * 2048 + q0 + l31) * 2048 + h * 64;
  ushort* ObB = O + (size_t)(b * 2048 + q0 + 32 + l31) * 2048 + h * 64;
#pragma unroll
  for (int rg = 0; rg < 4; ++rg) {
    ushort4 o0, o1;
    o0.x = f2bf(accA0[rg * 4 + 0] * invA);
    o0.y = f2bf(accA0[rg * 4 + 1] * invA);
    o0.z = f2bf(accA0[rg * 4 + 2] * invA);
    o0.w = f2bf(accA0[rg * 4 + 3] * invA);
    o1.x = f2bf(accA1[rg * 4 + 0] * invA);
    o1.y = f2bf(accA1[rg * 4 + 1] * invA);
    o1.z = f2bf(accA1[rg * 4 + 2] * invA);
    o1.w = f2bf(accA1[rg * 4 + 3] * invA);
    *(ushort4*)(ObA + rg * 8 + hi * 4) = o0;
    *(ushort4*)(ObA + 32 + rg * 8 + hi * 4) = o1;
    o0.x = f2bf(accB0[rg * 4 + 0] * invB);
    o0.y = f2bf(accB0[rg * 4 + 1] * invB);
    o0.z = f2bf(accB0[rg * 4 + 2] * invB);
    o0.w = f2bf(accB0[rg * 4 + 3] * invB);
    o1.x = f2bf(accB1[rg * 4 + 0] * invB);
    o1.y = f2bf(accB1[rg * 4 + 1] * invB);
    o1.z = f2bf(accB1[rg * 4 + 2] * invB);
    o1.w = f2bf(accB1[rg * 4 + 3] * invB);
    *(ushort4*)(ObB + rg * 8 + hi * 4) = o0;
    *(ushort4*)(ObB + 32 + rg * 8 + hi * 4) = o1;
  }
}

// ---------------------------------------------------------------------------
extern "C" void kernel_launch(void* const* d_in, const int* in_sizes, int n_in,
                              void* d_out, int out_size, void* d_ws, size_t ws_size,
                              hipStream_t stream) {
  (void)in_sizes; (void)n_in; (void)out_size; (void)ws_size;
  const float* x = (const float*)d_in[0];
  const float* Wq = (const float*)d_in[1];
  const float* Wk = (const float*)d_in[2];
  const float* Wv = (const float*)d_in[3];
  const float* Wo = (const float*)d_in[4];
  float* out = (float*)d_out;

  char* ws = (char*)d_ws;
  size_t off = 0;
  auto take = [&](size_t bytes) {
    void* p = ws + off;
    off += (bytes + 255) & ~(size_t)255;
    return p;
  };
  ushort* xbf = (ushort*)take(16777216);   // x bf16 [4096][2048]
  ushort* wqbf = (ushort*)take(8388608);
  ushort* wkbf = (ushort*)take(2097152);
  ushort* wvbf = (ushort*)take(2097152);
  ushort* wobf = (ushort*)take(8388608);
  ushort* Qbf = (ushort*)take(16777216);   // [2][32][2048][64]
  ushort* Kbf = (ushort*)take(4194304);    // [2][8][2048][64]
  ushort* Vtb = (ushort*)take(4194304);    // [2][8][64][2048]
  ushort* attnout = (ushort*)take(16777216);  // [4096][2048]
  float* tabc = (float*)take(262144);      // [2048][32]
  float* tabs = (float*)take(262144);

  prep_kernel<<<9472, 256, 0, stream>>>(x, Wq, Wk, Wv, Wo, xbf, wqbf, wkbf,
                                        wvbf, wobf, tabc, tabs);
  gemm_qkv_kernel<<<768, 256, 0, stream>>>(xbf, wqbf, wkbf, wvbf, Qbf, Kbf,
                                           Vtb, tabc, tabs);
  attn_kernel<<<512, 256, 0, stream>>>(Qbf, Kbf, Vtb, attnout);
  gemm_o_kernel<<<512, 256, 0, stream>>>(attnout, wobf, out);
}

// Round 17
// 205.584 us; speedup vs baseline: 1.2005x; 1.2005x over previous
//
#include <hip/hip_runtime.h>
#include <hip/hip_bf16.h>

// ---------------------------------------------------------------------------
// GQA attention block: y = Attn(RoPE(xWq^T), RoPE(xWk^T), xWv^T) Wo^T
// B=2, S=2048, D=2048, Hq=32, Hkv=8, hd=64, G=4, non-causal, scale=1/8.
// Pipeline (4 kernels): prep(cast+table) -> gemm_qkv(+fused rope/layout)
//                       -> attn -> gemm_o (dbuf + counted vmcnt).
// Empirically optimal configuration (benched 205.8/205.9 us, rounds 11/15).
// Structural variants all measured worse: bigger attn phases spill (R12/R16),
// kv-split nulls (R13), forced 3-waves spills (R14), 1 q-tile/wave is slower
// (R9). attn is pinned at 2 waves/SIMD by its 176-reg working set.
// ---------------------------------------------------------------------------

typedef __attribute__((ext_vector_type(8))) short short8;
typedef __attribute__((ext_vector_type(4))) float f32x4;
typedef __attribute__((ext_vector_type(16))) float f32x16;

#define MFMA16(A, B, C) __builtin_amdgcn_mfma_f32_16x16x32_bf16((A), (B), (C), 0, 0, 0)
#define MFMA32(A, B, C) __builtin_amdgcn_mfma_f32_32x32x16_bf16((A), (B), (C), 0, 0, 0)

__device__ __forceinline__ ushort f2bf(float f) {
  __hip_bfloat16 h = __float2bfloat16(f);
  return __builtin_bit_cast(ushort, h);
}

// Raw v_exp_f32 (exp2). OCML's exp2f is a multi-instr sequence; this is 1.
__device__ __forceinline__ float fexp2(float x) {
#if __has_builtin(__builtin_amdgcn_exp2f)
  return __builtin_amdgcn_exp2f(x);
#else
  float r;
  asm("v_exp_f32 %0, %1" : "=v"(r) : "v"(x));
  return r;
#endif
}

__device__ __forceinline__ void gload_lds16(const void* g, void* l) {
  __builtin_amdgcn_global_load_lds(
      (const __attribute__((address_space(1))) unsigned int*)g,
      (__attribute__((address_space(3))) unsigned int*)l, 16, 0, 0);
}

// ---------------- fused prep: fp32->bf16 casts + RoPE table ----------------
__global__ __launch_bounds__(256) void prep_kernel(
    const float* __restrict__ x, const float* __restrict__ Wq,
    const float* __restrict__ Wk, const float* __restrict__ Wv,
    const float* __restrict__ Wo, ushort* __restrict__ xbf,
    ushort* __restrict__ wqbf, ushort* __restrict__ wkbf,
    ushort* __restrict__ wvbf, ushort* __restrict__ wobf,
    float* __restrict__ tc, float* __restrict__ ts) {
  const int blk = blockIdx.x;
  if (blk < 9216) {
    const float* src;
    ushort* dst;
    int t;
    if (blk < 4096) {
      src = x; dst = xbf; t = blk * 256 + threadIdx.x;
    } else if (blk < 6144) {
      src = Wq; dst = wqbf; t = (blk - 4096) * 256 + threadIdx.x;
    } else if (blk < 6656) {
      src = Wk; dst = wkbf; t = (blk - 6144) * 256 + threadIdx.x;
    } else if (blk < 7168) {
      src = Wv; dst = wvbf; t = (blk - 6656) * 256 + threadIdx.x;
    } else {
      src = Wo; dst = wobf; t = (blk - 7168) * 256 + threadIdx.x;
    }
    const float4* p = (const float4*)src;
    float4 a = p[t * 2], b = p[t * 2 + 1];
    int4 o;
    o.x = (int)f2bf(a.x) | ((int)f2bf(a.y) << 16);
    o.y = (int)f2bf(a.z) | ((int)f2bf(a.w) << 16);
    o.z = (int)f2bf(b.x) | ((int)f2bf(b.y) << 16);
    o.w = (int)f2bf(b.z) | ((int)f2bf(b.w) << 16);
    ((int4*)dst)[t] = o;
  } else {
    int t = (blk - 9216) * 256 + threadIdx.x;  // 2048*32
    int j = t & 31, s = t >> 5;
    float freq = powf(10000.0f, -(float)j * (1.0f / 32.0f));
    float ang = (float)s * freq;
    tc[t] = cosf(ang);
    ts[t] = sinf(ang);
  }
}

// ---------------- 128x128 bf16 GEMM core, BK=64, XOR-8 swizzled LDS --------
// Single-buffered variant (2 barriers/step) — used by gemm_qkv whose 768-tile
// grid fits exactly 3 blocks/CU at 32KB LDS.
__device__ __forceinline__ void gemm_core(const ushort* __restrict__ A,
                                          const ushort* __restrict__ Bt,
                                          int row0, int col0, int K,
                                          f32x4 (&acc)[4][4]) {
  __shared__ __align__(16) ushort As[8192];  // [128 rows][8 chunks of 16B]
  __shared__ __align__(16) ushort Bs[8192];
  const int t = threadIdx.x;
  const int lane = t & 63, wid = t >> 6;
  const int lr = lane & 15, lh = lane >> 4;
  const int wm = wid >> 1, wn = wid & 1;
#pragma unroll
  for (int i = 0; i < 4; ++i)
#pragma unroll
    for (int j = 0; j < 4; ++j) acc[i][j] = (f32x4){0.f, 0.f, 0.f, 0.f};

  const int srow = t >> 3, scg = (t & 7) ^ (srow & 7);
  const ushort* Asrc = A + (size_t)(row0 + srow) * K + scg * 8;
  const ushort* Bsrc = Bt + (size_t)(col0 + srow) * K + scg * 8;
  char* AsB = (char*)As + wid * 1024;
  char* BsB = (char*)Bs + wid * 1024;
  const int s7a = lr & 7;

  for (int k0 = 0; k0 < K; k0 += 64) {
    __syncthreads();  // previous iteration's reads done
#pragma unroll
    for (int i = 0; i < 4; ++i) {
      gload_lds16(Asrc + (size_t)(32 * i) * K + k0, AsB + i * 4096);
      gload_lds16(Bsrc + (size_t)(32 * i) * K + k0, BsB + i * 4096);
    }
    __syncthreads();  // staging visible

    short8 af[4][2];
#pragma unroll
    for (int fm = 0; fm < 4; ++fm)
#pragma unroll
      for (int kk = 0; kk < 2; ++kk)
        af[fm][kk] = *(const short8*)((const char*)As +
                                      ((wm * 64 + fm * 16 + lr) << 7) +
                                      (((kk * 4 + lh) ^ s7a) << 4));
#pragma unroll
    for (int kk = 0; kk < 2; ++kk)
#pragma unroll
      for (int fn = 0; fn < 4; ++fn) {
        short8 bf_ = *(const short8*)((const char*)Bs +
                                      ((wn * 64 + fn * 16 + lr) << 7) +
                                      (((kk * 4 + lh) ^ s7a) << 4));
#pragma unroll
        for (int fm = 0; fm < 4; ++fm)
          acc[fm][fn] = MFMA16(af[fm][kk], bf_, acc[fm][fn]);
      }
  }
}

// Double-buffered variant with COUNTED vmcnt (T3/T4): 16 loads in flight at
// steady state, vmcnt(8) per step (never 0 until the last tile). LDS 64KB ->
// 2 blocks/CU; used by gemm_o whose 512-block grid is exactly 2/CU.
__device__ __forceinline__ void gemm_core_db(const ushort* __restrict__ A,
                                             const ushort* __restrict__ Bt,
                                             int row0, int col0, int K,
                                             f32x4 (&acc)[4][4]) {
  __shared__ __align__(16) ushort As[16384];  // 2 x [128 rows][8 chunks]
  __shared__ __align__(16) ushort Bs[16384];
  const int t = threadIdx.x;
  const int lane = t & 63, wid = t >> 6;
  const int lr = lane & 15, lh = lane >> 4;
  const int wm = wid >> 1, wn = wid & 1;
#pragma unroll
  for (int i = 0; i < 4; ++i)
#pragma unroll
    for (int j = 0; j < 4; ++j) acc[i][j] = (f32x4){0.f, 0.f, 0.f, 0.f};

  const int srow = t >> 3, scg = (t & 7) ^ (srow & 7);
  const ushort* Asrc = A + (size_t)(row0 + srow) * K + scg * 8;
  const ushort* Bsrc = Bt + (size_t)(col0 + srow) * K + scg * 8;
  const int s7a = lr & 7;

#define GSTAGE(PAR, KOFF)                                                    \
  do {                                                                       \
    char* a_ = (char*)As + (PAR) * 16384 + wid * 1024;                       \
    char* b_ = (char*)Bs + (PAR) * 16384 + wid * 1024;                       \
    _Pragma("unroll") for (int i_ = 0; i_ < 4; ++i_) {                       \
      gload_lds16(Asrc + (size_t)(32 * i_) * K + (KOFF), a_ + i_ * 4096);    \
      gload_lds16(Bsrc + (size_t)(32 * i_) * K + (KOFF), b_ + i_ * 4096);    \
    }                                                                        \
  } while (0)

  GSTAGE(0, 0);
  GSTAGE(1, 64);
  const int nstep = K >> 6;
  for (int it = 0; it < nstep; ++it) {
    if (it + 1 < nstep)
      asm volatile("s_waitcnt vmcnt(8)" ::: "memory");
    else
      asm volatile("s_waitcnt vmcnt(0)" ::: "memory");
    __builtin_amdgcn_s_barrier();  // all waves staged tile 'it'
    {
      const char* ab_ = (const char*)As + (it & 1) * 16384;
      const char* bb_ = (const char*)Bs + (it & 1) * 16384;
      short8 af[4][2];
#pragma unroll
      for (int fm = 0; fm < 4; ++fm)
#pragma unroll
        for (int kk = 0; kk < 2; ++kk)
          af[fm][kk] = *(const short8*)(ab_ + ((wm * 64 + fm * 16 + lr) << 7) +
                                        (((kk * 4 + lh) ^ s7a) << 4));
#pragma unroll
      for (int kk = 0; kk < 2; ++kk)
#pragma unroll
        for (int fn = 0; fn < 4; ++fn) {
          short8 bf_ = *(const short8*)(bb_ + ((wn * 64 + fn * 16 + lr) << 7) +
                                        (((kk * 4 + lh) ^ s7a) << 4));
#pragma unroll
          for (int fm = 0; fm < 4; ++fm)
            acc[fm][fn] = MFMA16(af[fm][kk], bf_, acc[fm][fn]);
        }
    }
    __builtin_amdgcn_s_barrier();  // all waves done reading buf (it&1)
    if (it + 2 < nstep) GSTAGE(it & 1, (it + 2) * 64);
  }
#undef GSTAGE
}

// QKV projection with fused RoPE + head-split + V-transpose epilogue.
// Q out: [B][32][S][64] bf16 scaled by 1/(8*ln2); K out: [B][8][S][64];
// V out: [B][8][64][S] (transposed).
__global__ __launch_bounds__(256) void gemm_qkv_kernel(
    const ushort* __restrict__ xbf, const ushort* __restrict__ wq,
    const ushort* __restrict__ wk, const ushort* __restrict__ wv,
    ushort* __restrict__ Qo, ushort* __restrict__ Ko, ushort* __restrict__ Vo,
    const float* __restrict__ tabc, const float* __restrict__ tabs) {
  int bx = blockIdx.x % 24, by = blockIdx.x / 24;
  const ushort* Bt;
  int cb;
  if (bx < 16) {
    Bt = wq; cb = bx;
  } else if (bx < 20) {
    Bt = wk; cb = bx - 16;
  } else {
    Bt = wv; cb = bx - 20;
  }
  f32x4 acc[4][4];
  gemm_core(xbf, Bt, by * 128, cb * 128, 2048, acc);

  const int lane = threadIdx.x & 63, wid = threadIdx.x >> 6;
  const int lr = lane & 15, lh = lane >> 4;
  const int wm = wid >> 1, wn = wid & 1;
  const int srow0 = by * 128 + wm * 64 + lh * 4;

  if (bx >= 20) {
    const int kv = cb * 2 + wn;
#pragma unroll
    for (int fm = 0; fm < 4; ++fm) {
      int srow = srow0 + fm * 16;
      int bb = srow >> 11, s = srow & 2047;
#pragma unroll
      for (int fn = 0; fn < 4; ++fn) {
        int d = fn * 16 + lr;
        ushort4 o;
        o.x = f2bf(acc[fm][fn][0]);
        o.y = f2bf(acc[fm][fn][1]);
        o.z = f2bf(acc[fm][fn][2]);
        o.w = f2bf(acc[fm][fn][3]);
        *(ushort4*)&Vo[((size_t)((bb * 8 + kv) * 64 + d)) * 2048 + s] = o;
      }
    }
  } else {
    ushort* dst;
    int nh, h;
    float scale;
    if (bx < 16) {
      dst = Qo; nh = 32; h = bx * 2 + wn;
      scale = 0.125f * 1.44269504088896340736f;  // softmax scale * 1/ln2
    } else {
      dst = Ko; nh = 8; h = cb * 2 + wn; scale = 1.0f;
    }
#pragma unroll
    for (int fm = 0; fm < 4; ++fm) {
      int srow = srow0 + fm * 16;
      int bb = srow >> 11, sbase = srow & 2047;
      size_t obase = (size_t)(bb * nh + h) * 2048;
#pragma unroll
      for (int fn = 0; fn < 2; ++fn) {
        int j = fn * 16 + lr;
#pragma unroll
        for (int r = 0; r < 4; ++r) {
          int s = sbase + r;
          float c = tabc[s * 32 + j], sn = tabs[s * 32 + j];
          float x1 = acc[fm][fn][r], x2 = acc[fm][fn + 2][r];
          ushort* po = &dst[(obase + s) * 64 + j];
          po[0] = f2bf((x1 * c - x2 * sn) * scale);
          po[32] = f2bf((x2 * c + x1 * sn) * scale);
        }
      }
    }
  }
}

__global__ __launch_bounds__(256, 2) void gemm_o_kernel(const ushort* __restrict__ A,
                                                        const ushort* __restrict__ Wo,
                                                        float* __restrict__ C) {
  int bx = blockIdx.x & 15, by = blockIdx.x >> 4;
  int row0 = by * 128, col0 = bx * 128;
  f32x4 acc[4][4];
  gemm_core_db(A, Wo, row0, col0, 2048, acc);
  const int lane = threadIdx.x & 63, wid = threadIdx.x >> 6;
  const int lr = lane & 15, lh = lane >> 4;
  const int wm = wid >> 1, wn = wid & 1;
#pragma unroll
  for (int fm = 0; fm < 4; ++fm) {
    int r0 = row0 + wm * 64 + fm * 16 + lh * 4;
#pragma unroll
    for (int fn = 0; fn < 4; ++fn) {
      int cc = col0 + wn * 64 + fn * 16 + lr;
#pragma unroll
      for (int r = 0; r < 4; ++r) C[(size_t)(r0 + r) * 2048 + cc] = acc[fm][fn][r];
    }
  }
}

// ---------------- flash attention: LDS-staged K/V, 32x32 MFMA --------------
// Q: [B][32][S][64] bf16 pre-scaled; K: [B][8][S][64]; Vt: [B][8][64][S];
// O: [B*S][2048] bf16. Block = 4 waves = 4 q-heads of one GQA group; each
// wave owns TWO 32-row q-tiles (q0, q0+32) so every K/V ds_read feeds two
// MFMAs and the two chains overlap. 64-kv tiles double-buffered in LDS, one
// barrier per tile. Softmax is UNNORMALIZED exp2 via raw v_exp_f32 (scores
// bounded, sums cancel in the final /ls).
__global__ __launch_bounds__(256, 2) void attn_kernel(const ushort* __restrict__ Q,
                                                      const ushort* __restrict__ Kg,
                                                      const ushort* __restrict__ Vt,
                                                      ushort* __restrict__ O) {
  __shared__ __align__(16) char smem_c[32768];  // K dbuf @0/8192, V dbuf @16384/24576
  const int tid = threadIdx.x;
  const int lane = tid & 63;
  const int wid = tid >> 6;
  const int bid = ((blockIdx.x & 7) << 6) | (blockIdx.x >> 3);  // XCD swizzle
  const int qp = bid & 31;
  const int kvh = (bid >> 5) & 7;
  const int b = bid >> 8;
  const int h = kvh * 4 + wid;  // wave = one q-head of the group
  const int q0 = qp * 64;      // wave covers q0..q0+63 (two 32-row tiles)
  const int l31 = lane & 31;
  const int hi = lane >> 5;

  const ushort* Qp = Q + ((size_t)((b * 32 + h) * 2048 + q0)) * 64;
  const ushort* Kp = Kg + ((size_t)((b * 8 + kvh) * 2048)) * 64;
  const ushort* Vp = Vt + ((size_t)((b * 8 + kvh) * 64)) * 2048;

  // Staging (pre-swizzled global, linear LDS dest): tiles are [64 rows][8
  // chunks of 16B]; thread t stages chunks t and t+256 (rows r, r+32).
  const int srow = tid >> 3, scg = (tid & 7) ^ (srow & 7);
  const ushort* Kst = Kp + (size_t)srow * 64 + scg * 8;
  const ushort* Vst = Vp + (size_t)srow * 2048 + scg * 8;

#define STAGE(PAR, KV0)                                                         \
  do {                                                                          \
    char* kd_ = smem_c + (PAR) * 8192 + wid * 1024;                             \
    char* vd_ = smem_c + 16384 + (PAR) * 8192 + wid * 1024;                     \
    gload_lds16(Kst + (size_t)(KV0) * 64, kd_);                                 \
    gload_lds16(Kst + (size_t)((KV0) + 32) * 64, kd_ + 4096);                   \
    gload_lds16(Vst + (KV0), vd_);                                              \
    gload_lds16(Vst + 32 * 2048 + (KV0), vd_ + 4096);                           \
  } while (0)

  STAGE(0, 0);  // tile 0 in flight immediately

  // Q B-frags for the two q-tiles.
  const short8 qfA0 = *(const short8*)(Qp + (size_t)l31 * 64 + 0 + hi * 8);
  const short8 qfA1 = *(const short8*)(Qp + (size_t)l31 * 64 + 16 + hi * 8);
  const short8 qfA2 = *(const short8*)(Qp + (size_t)l31 * 64 + 32 + hi * 8);
  const short8 qfA3 = *(const short8*)(Qp + (size_t)l31 * 64 + 48 + hi * 8);
  const short8 qfB0 = *(const short8*)(Qp + (size_t)(32 + l31) * 64 + 0 + hi * 8);
  const short8 qfB1 = *(const short8*)(Qp + (size_t)(32 + l31) * 64 + 16 + hi * 8);
  const short8 qfB2 = *(const short8*)(Qp + (size_t)(32 + l31) * 64 + 32 + hi * 8);
  const short8 qfB3 = *(const short8*)(Qp + (size_t)(32 + l31) * 64 + 48 + hi * 8);

  const int s7 = l31 & 7;
  const int ok0 = l31 * 128 + (((0 + hi) ^ s7) << 4);
  const int ok1 = l31 * 128 + (((2 + hi) ^ s7) << 4);
  const int ok2 = l31 * 128 + (((4 + hi) ^ s7) << 4);
  const int ok3 = l31 * 128 + (((6 + hi) ^ s7) << 4);

  f32x16 accA0, accA1, accB0, accB1, kz;
#pragma unroll
  for (int r = 0; r < 16; ++r) {
    accA0[r] = 0.f;
    accA1[r] = 0.f;
    accB0[r] = 0.f;
    accB1[r] = 0.f;
    kz[r] = 0.f;
  }
  float lshA = 0.f, lshB = 0.f;  // lane-half unnormalized sums

// QK^T for one 32-kv subtile, BOTH q-tiles; each K frag read feeds 2 MFMAs.
#define QK2(STA, STB, KOFF)                                  \
  do {                                                       \
    const char* kb_ = smem_c + (KOFF);                       \
    short8 kf_ = *(const short8*)(kb_ + ok0);                \
    __builtin_amdgcn_s_setprio(1);                           \
    STA = MFMA32(kf_, qfA0, kz);                             \
    STB = MFMA32(kf_, qfB0, kz);                             \
    kf_ = *(const short8*)(kb_ + ok1);                       \
    STA = MFMA32(kf_, qfA1, STA);                            \
    STB = MFMA32(kf_, qfB1, STB);                            \
    kf_ = *(const short8*)(kb_ + ok2);                       \
    STA = MFMA32(kf_, qfA2, STA);                            \
    STB = MFMA32(kf_, qfB2, STB);                            \
    kf_ = *(const short8*)(kb_ + ok3);                       \
    STA = MFMA32(kf_, qfA3, STA);                            \
    STB = MFMA32(kf_, qfB3, STB);                            \
    __builtin_amdgcn_s_setprio(0);                           \
  } while (0)

// Unnormalized softmax: ST -> P fragments (F0,F1) + half-sum LSH.
#define SMX(ST, F0, F1, LSH)                                                  \
  do {                                                                        \
    float ps_ = 0.f;                                                          \
    uint pk0_, pk1_, pk2_, pk3_, pk4_, pk5_, pk6_, pk7_;                      \
    _Pragma("unroll") for (int j = 0; j < 8; ++j) {                           \
      float pa_ = fexp2(ST[2 * j]);                                           \
      float pb_ = fexp2(ST[2 * j + 1]);                                       \
      ps_ += pa_ + pb_;                                                       \
      uint w_ = __builtin_amdgcn_perm(__builtin_bit_cast(uint, pb_),          \
                                      __builtin_bit_cast(uint, pa_),          \
                                      0x07060302u);                           \
      switch (j) {                                                            \
        case 0: pk0_ = w_; break;                                             \
        case 1: pk1_ = w_; break;                                             \
        case 2: pk2_ = w_; break;                                             \
        case 3: pk3_ = w_; break;                                             \
        case 4: pk4_ = w_; break;                                             \
        case 5: pk5_ = w_; break;                                             \
        case 6: pk6_ = w_; break;                                             \
        default: pk7_ = w_; break;                                            \
      }                                                                       \
    }                                                                         \
    LSH += ps_;                                                               \
    uint u0_ = hi ? pk0_ : pk2_; u0_ = __shfl_xor(u0_, 32);                   \
    uint u1_ = hi ? pk1_ : pk3_; u1_ = __shfl_xor(u1_, 32);                   \
    uint u2_ = hi ? pk4_ : pk6_; u2_ = __shfl_xor(u2_, 32);                   \
    uint u3_ = hi ? pk5_ : pk7_; u3_ = __shfl_xor(u3_, 32);                   \
    F0.u[0] = hi ? u0_ : pk0_;                                                \
    F0.u[1] = hi ? u1_ : pk1_;                                                \
    F0.u[2] = hi ? pk2_ : u0_;                                                \
    F0.u[3] = hi ? pk3_ : u1_;                                                \
    F1.u[0] = hi ? u2_ : pk4_;                                                \
    F1.u[1] = hi ? u3_ : pk5_;                                                \
    F1.u[2] = hi ? pk6_ : u2_;                                                \
    F1.u[3] = hi ? pk7_ : u3_;                                                \
  } while (0)

// Softmax + PV for one subtile, both q-tiles; V reads shared.
#define SMPV2(STA, STB, VOFF, VSX)                                           \
  do {                                                                       \
    union { uint u[4]; short8 s; } fA0_, fA1_, fB0_, fB1_;                   \
    SMX(STA, fA0_, fA1_, lshA);                                              \
    SMX(STB, fB0_, fB1_, lshB);                                              \
    const char* vb_ = smem_c + (VOFF);                                       \
    short8 v0_ = *(const short8*)(vb_ + (ok0 ^ (VSX)));                      \
    short8 v1_ = *(const short8*)(vb_ + (ok1 ^ (VSX)));                      \
    __builtin_amdgcn_s_setprio(1);                                           \
    accA0 = MFMA32(v0_, fA0_.s, accA0);                                      \
    accA0 = MFMA32(v1_, fA1_.s, accA0);                                      \
    accB0 = MFMA32(v0_, fB0_.s, accB0);                                      \
    accB0 = MFMA32(v1_, fB1_.s, accB0);                                      \
    __builtin_amdgcn_s_setprio(0);                                           \
    v0_ = *(const short8*)(vb_ + (ok0 ^ (VSX)) + 4096);                      \
    v1_ = *(const short8*)(vb_ + (ok1 ^ (VSX)) + 4096);                      \
    __builtin_amdgcn_s_setprio(1);                                           \
    accA1 = MFMA32(v0_, fA0_.s, accA1);                                      \
    accA1 = MFMA32(v1_, fA1_.s, accA1);                                      \
    accB1 = MFMA32(v0_, fB0_.s, accB1);                                      \
    accB1 = MFMA32(v1_, fB1_.s, accB1);                                      \
    __builtin_amdgcn_s_setprio(0);                                           \
  } while (0)

  for (int t = 0; t < 32; ++t) {
    asm volatile("s_waitcnt vmcnt(0)" ::: "memory");  // my tile-t loads landed
    __builtin_amdgcn_s_barrier();  // all waves: tile t staged, buf^1 readers done
    if (t < 31) STAGE((t + 1) & 1, (t + 1) * 64);  // prefetch under compute
    {
      const int kb = (t & 1) * 8192;
      const int vb = 16384 + (t & 1) * 8192;
      f32x16 stA0_, stB0_, stA1_, stB1_;
      QK2(stA0_, stB0_, kb);
      QK2(stA1_, stB1_, kb + 4096);  // overlaps subtile-0 softmax below
      SMPV2(stA0_, stB0_, vb, 0);
      SMPV2(stA1_, stB1_, vb, 64);
    }
  }
#undef STAGE
#undef QK2
#undef SMX
#undef SMPV2

  const float lsA = lshA + __shfl_xor(lshA, 32);
  const float lsB = lshB + __shfl_xor(lshB, 32);
  const float invA = 1.0f / lsA;
  const float invB = 1.0f / lsB;
  ushort* ObA = O + (size_t)(b * 2048 + q0 + l31) * 2048 + h * 64;
  ushort* ObB = O + (size_t)(b * 2048 + q0 + 32 + l31) * 2048 + h * 64;
#pragma unroll
  for (int rg = 0; rg < 4; ++rg) {
    ushort4 o0, o1;
    o0.x = f2bf(accA0[rg * 4 + 0] * invA);
    o0.y = f2bf(accA0[rg * 4 + 1] * invA);
    o0.z = f2bf(accA0[rg * 4 + 2] * invA);
    o0.w = f2bf(accA0[rg * 4 + 3] * invA);
    o1.x = f2bf(accA1[rg * 4 + 0] * invA);
    o1.y = f2bf(accA1[rg * 4 + 1] * invA);
    o1.z = f2bf(accA1[rg * 4 + 2] * invA);
    o1.w = f2bf(accA1[rg * 4 + 3] * invA);
    *(ushort4*)(ObA + rg * 8 + hi * 4) = o0;
    *(ushort4*)(ObA + 32 + rg * 8 + hi * 4) = o1;
    o0.x = f2bf(accB0[rg * 4 + 0] * invB);
    o0.y = f2bf(accB0[rg * 4 + 1] * invB);
    o0.z = f2bf(accB0[rg * 4 + 2] * invB);
    o0.w = f2bf(accB0[rg * 4 + 3] * invB);
    o1.x = f2bf(accB1[rg * 4 + 0] * invB);
    o1.y = f2bf(accB1[rg * 4 + 1] * invB);
    o1.z = f2bf(accB1[rg * 4 + 2] * invB);
    o1.w = f2bf(accB1[rg * 4 + 3] * invB);
    *(ushort4*)(ObB + rg * 8 + hi * 4) = o0;
    *(ushort4*)(ObB + 32 + rg * 8 + hi * 4) = o1;
  }
}

// ---------------------------------------------------------------------------
extern "C" void kernel_launch(void* const* d_in, const int* in_sizes, int n_in,
                              void* d_out, int out_size, void* d_ws, size_t ws_size,
                              hipStream_t stream) {
  (void)in_sizes; (void)n_in; (void)out_size; (void)ws_size;
  const float* x = (const float*)d_in[0];
  const float* Wq = (const float*)d_in[1];
  const float* Wk = (const float*)d_in[2];
  const float* Wv = (const float*)d_in[3];
  const float* Wo = (const float*)d_in[4];
  float* out = (float*)d_out;

  char* ws = (char*)d_ws;
  size_t off = 0;
  auto take = [&](size_t bytes) {
    void* p = ws + off;
    off += (bytes + 255) & ~(size_t)255;
    return p;
  };
  ushort* xbf = (ushort*)take(16777216);   // x bf16 [4096][2048]
  ushort* wqbf = (ushort*)take(8388608);
  ushort* wkbf = (ushort*)take(2097152);
  ushort* wvbf = (ushort*)take(2097152);
  ushort* wobf = (ushort*)take(8388608);
  ushort* Qbf = (ushort*)take(16777216);   // [2][32][2048][64]
  ushort* Kbf = (ushort*)take(4194304);    // [2][8][2048][64]
  ushort* Vtb = (ushort*)take(4194304);    // [2][8][64][2048]
  ushort* attnout = (ushort*)take(16777216);  // [4096][2048]
  float* tabc = (float*)take(262144);      // [2048][32]
  float* tabs = (float*)take(262144);

  prep_kernel<<<9472, 256, 0, stream>>>(x, Wq, Wk, Wv, Wo, xbf, wqbf, wkbf,
                                        wvbf, wobf, tabc, tabs);
  gemm_qkv_kernel<<<768, 256, 0, stream>>>(xbf, wqbf, wkbf, wvbf, Qbf, Kbf,
                                           Vtb, tabc, tabs);
  attn_kernel<<<512, 256, 0, stream>>>(Qbf, Kbf, Vtb, attnout);
  gemm_o_kernel<<<512, 256, 0, stream>>>(attnout, wobf, out);
}